// Round 1
// baseline (405.568 us; speedup 1.0000x reference)
//
#include <hip/hip_runtime.h>
#include <hip/hip_bf16.h>

// SingleHeadAttention: embedded [4,4096,1024] f32; Wk/Wq/Wv [128,1024] f32.
// out = causal_softmax((emb Wq^T)(emb Wk^T)^T / sqrt(128)) (emb Wv^T), f32 [4,4096,128].
//
// Plan: bf16 MFMA throughout (threshold 3.55e-2 permits bf16 compute).
//  K1: QKV projection GEMM -> ws holds Q (prescaled 1/sqrt(128)), K row-major, V^T, all bf16.
//  K2: flash-style causal attention, 64-q tile/block, 64-k tiles, online softmax.
// MFMA fragment layouts (gfx950, measured learn_hip m89/m91/m120):
//  A: m = lane&15, k = (lane>>4)*8 + j  (8 contiguous bf16)
//  B: n = lane&15, k = (lane>>4)*8 + j  (8 contiguous bf16)
//  C/D: col = lane&15, row = (lane>>4)*4 + reg

#define SEQ 4096
#define BATCH 4

typedef unsigned short u16;
typedef __bf16 bf16x8 __attribute__((ext_vector_type(8)));
typedef float f32x4 __attribute__((ext_vector_type(4)));

__device__ __forceinline__ u16 f2bf(float f) {
    union { float f; unsigned u; } v; v.f = f;
    unsigned u = v.u;
    return (u16)((u + 0x7FFFu + ((u >> 16) & 1u)) >> 16);  // RNE, inputs finite
}

// ---------------- Kernel 1: QKV projection ----------------
// Grid 256 blocks x 256 thr. Block: 64 emb rows; all 3*128 output cols.
// K=1024 in 16 chunks of 64. Per wave: 16 rows, 24 col-tiles, 48 mfma/chunk.
__global__ __launch_bounds__(256) void qkv_kernel(
    const float* __restrict__ emb, const float* __restrict__ Wk,
    const float* __restrict__ Wq, const float* __restrict__ Wv,
    u16* __restrict__ Qws, u16* __restrict__ Kws, u16* __restrict__ Vtws)
{
    __shared__ u16 sE[64][72];        // +8 pad: 2-way bank alias only (free)
    __shared__ u16 sW[3][128][72];

    const int tid  = threadIdx.x;
    const int wv   = tid >> 6;
    const int lane = tid & 63;
    const int quad = lane >> 4;
    const int l16  = lane & 15;
    const int r0   = blockIdx.x * 64;

    const float* Ws[3] = {Wk, Wq, Wv};  // order: K, Q, V

    f32x4 acc[24];
    #pragma unroll
    for (int t = 0; t < 24; t++) acc[t] = (f32x4){0.f, 0.f, 0.f, 0.f};

    for (int kc = 0; kc < 1024; kc += 64) {
        __syncthreads();
        // stage emb chunk [64 x 64] f32 -> bf16
        #pragma unroll
        for (int i = 0; i < 4; i++) {
            int idx = tid + i * 256;              // 0..1023
            int row = idx >> 4, c4 = idx & 15;
            const float4 v = *(const float4*)&emb[(size_t)(r0 + row) * 1024 + kc + c4 * 4];
            ushort4 o; o.x = f2bf(v.x); o.y = f2bf(v.y); o.z = f2bf(v.z); o.w = f2bf(v.w);
            *(ushort4*)&sE[row][c4 * 4] = o;
        }
        // stage 3 W chunks [128 x 64] each
        #pragma unroll
        for (int i = 0; i < 8; i++) {
            int idx = tid + i * 256;              // 0..2047
            int row = idx >> 4, c4 = idx & 15;
            #pragma unroll
            for (int m = 0; m < 3; m++) {
                const float4 v = *(const float4*)&Ws[m][(size_t)row * 1024 + kc + c4 * 4];
                ushort4 o; o.x = f2bf(v.x); o.y = f2bf(v.y); o.z = f2bf(v.z); o.w = f2bf(v.w);
                *(ushort4*)&sW[m][row][c4 * 4] = o;
            }
        }
        __syncthreads();

        bf16x8 a0 = *(const bf16x8*)&sE[wv * 16 + l16][quad * 8];
        bf16x8 a1 = *(const bf16x8*)&sE[wv * 16 + l16][32 + quad * 8];
        #pragma unroll
        for (int t = 0; t < 24; t++) {
            const u16* wrow = sW[t >> 3][(t & 7) * 16 + l16];
            acc[t] = __builtin_amdgcn_mfma_f32_16x16x32_bf16(
                a0, *(const bf16x8*)&wrow[quad * 8], acc[t], 0, 0, 0);
            acc[t] = __builtin_amdgcn_mfma_f32_16x16x32_bf16(
                a1, *(const bf16x8*)&wrow[32 + quad * 8], acc[t], 0, 0, 0);
        }
    }

    // epilogue: C/D row = quad*4+reg, col = l16 + nt*16
    const int rowbase = r0 + wv * 16 + quad * 4;
    #pragma unroll
    for (int t = 0; t < 24; t++) {
        const int mat = t >> 3, col = (t & 7) * 16 + l16;
        #pragma unroll
        for (int r = 0; r < 4; r++) {
            const int row = rowbase + r;
            const float v = acc[t][r];
            if (mat == 0) {
                Kws[(size_t)row * 128 + col] = f2bf(v);
            } else if (mat == 1) {
                // fold 1/sqrt(128) into Q
                Qws[(size_t)row * 128 + col] = f2bf(v * 0.08838834764831845f);
            } else {
                const int b = row >> 12, s = row & 4095;
                Vtws[((size_t)(b * 128 + col)) * SEQ + s] = f2bf(v);  // V transposed
            }
        }
    }
}

// ---------------- Kernel 2: flash causal attention ----------------
// Grid (64 q-tiles, 4 batches) x 256 thr. Block: 64 q rows; wave w owns rows w*16..+15.
__global__ __launch_bounds__(256) void attn_kernel(
    const u16* __restrict__ Qws, const u16* __restrict__ Kws,
    const u16* __restrict__ Vtws, float* __restrict__ out)
{
    __shared__ u16 sQ[64][136];
    __shared__ u16 sK[64][136];
    __shared__ u16 sV[128][72];       // V^T tile: [h][key]
    __shared__ u16 sP[4][16][72];     // per-wave P staging (C-layout -> A-layout)

    const int tid  = threadIdx.x;
    const int wv   = tid >> 6;
    const int lane = tid & 63;
    const int quad = lane >> 4;
    const int l16  = lane & 15;
    const int qt   = blockIdx.x;
    const int b    = blockIdx.y;
    const int q0   = qt * 64;

    // stage Q tile [64 x 128] bf16 (already scaled by 1/sqrt(128))
    #pragma unroll
    for (int i = 0; i < 4; i++) {
        int idx = tid + i * 256;                  // 0..1023 chunks of 8 u16
        int row = idx >> 4, c8 = idx & 15;
        *(uint4*)&sQ[row][c8 * 8] =
            *(const uint4*)&Qws[((size_t)(b * SEQ + q0 + row)) * 128 + c8 * 8];
    }

    float m_i[4], l_i[4];
    f32x4 Oacc[8];
    #pragma unroll
    for (int r = 0; r < 4; r++) { m_i[r] = -3.0e38f; l_i[r] = 0.f; }
    #pragma unroll
    for (int h = 0; h < 8; h++) Oacc[h] = (f32x4){0.f, 0.f, 0.f, 0.f};

    for (int kt = 0; kt <= qt; kt++) {
        const int kbase = kt * 64;
        __syncthreads();  // prior-iter readers of sK/sV done (covers sQ staging on kt==0)
        #pragma unroll
        for (int i = 0; i < 4; i++) {             // K tile [64 x 128]
            int idx = tid + i * 256;
            int row = idx >> 4, c8 = idx & 15;
            *(uint4*)&sK[row][c8 * 8] =
                *(const uint4*)&Kws[((size_t)(b * SEQ + kbase + row)) * 128 + c8 * 8];
        }
        #pragma unroll
        for (int i = 0; i < 4; i++) {             // V^T tile [128 x 64]
            int idx = tid + i * 256;
            int row = idx >> 3, c8 = idx & 7;
            *(uint4*)&sV[row][c8 * 8] =
                *(const uint4*)&Vtws[((size_t)(b * 128 + row)) * SEQ + kbase + c8 * 8];
        }
        __syncthreads();

        // S = Q K^T  (per wave: [16 q x 64 k], 16 mfma, 4 indep chains)
        f32x4 s[4];
        #pragma unroll
        for (int nt = 0; nt < 4; nt++) s[nt] = (f32x4){0.f, 0.f, 0.f, 0.f};
        const u16* qrow = sQ[wv * 16 + l16];
        #pragma unroll
        for (int ks = 0; ks < 4; ks++) {
            bf16x8 a = *(const bf16x8*)&qrow[ks * 32 + quad * 8];
            #pragma unroll
            for (int nt = 0; nt < 4; nt++) {
                bf16x8 bfr = *(const bf16x8*)&sK[nt * 16 + l16][ks * 32 + quad * 8];
                s[nt] = __builtin_amdgcn_mfma_f32_16x16x32_bf16(a, bfr, s[nt], 0, 0, 0);
            }
        }

        // online softmax per row (rows quad*4+r; reduce across 16 lanes of quad)
        const int qglob = q0 + wv * 16 + quad * 4;
        float pv[4][4];  // [nt][r]
        #pragma unroll
        for (int r = 0; r < 4; r++) {
            #pragma unroll
            for (int nt = 0; nt < 4; nt++) {
                const int kg = kbase + nt * 16 + l16;
                if (kg > qglob + r) s[nt][r] = -3.0e38f;  // causal mask
            }
            float mx = fmaxf(fmaxf(s[0][r], s[1][r]), fmaxf(s[2][r], s[3][r]));
            mx = fmaxf(mx, __shfl_xor(mx, 1));
            mx = fmaxf(mx, __shfl_xor(mx, 2));
            mx = fmaxf(mx, __shfl_xor(mx, 4));
            mx = fmaxf(mx, __shfl_xor(mx, 8));
            const float mnew  = fmaxf(m_i[r], mx);
            const float alpha = exp2f((m_i[r] - mnew) * 1.4426950408889634f);
            m_i[r] = mnew;
            float rs = 0.f;
            #pragma unroll
            for (int nt = 0; nt < 4; nt++) {
                const float p = exp2f((s[nt][r] - mnew) * 1.4426950408889634f);
                pv[nt][r] = p;
                rs += p;
            }
            rs += __shfl_xor(rs, 1);
            rs += __shfl_xor(rs, 2);
            rs += __shfl_xor(rs, 4);
            rs += __shfl_xor(rs, 8);
            l_i[r] = l_i[r] * alpha + rs;
            #pragma unroll
            for (int h = 0; h < 8; h++) Oacc[h][r] *= alpha;
        }

        // P: C-layout regs -> LDS -> A-layout frags
        #pragma unroll
        for (int r = 0; r < 4; r++)
            #pragma unroll
            for (int nt = 0; nt < 4; nt++)
                sP[wv][quad * 4 + r][nt * 16 + l16] = f2bf(pv[nt][r]);
        __syncthreads();  // also guarantees own-wave ds_write->ds_read ordering

        // O += P V  (per wave: [16 q x 128 h], 16 mfma)
        const u16* prow = sP[wv][l16];
        bf16x8 a0 = *(const bf16x8*)&prow[quad * 8];
        bf16x8 a1 = *(const bf16x8*)&prow[32 + quad * 8];
        #pragma unroll
        for (int ht = 0; ht < 8; ht++) {
            const u16* vrow = sV[ht * 16 + l16];
            Oacc[ht] = __builtin_amdgcn_mfma_f32_16x16x32_bf16(
                a0, *(const bf16x8*)&vrow[quad * 8], Oacc[ht], 0, 0, 0);
            Oacc[ht] = __builtin_amdgcn_mfma_f32_16x16x32_bf16(
                a1, *(const bf16x8*)&vrow[32 + quad * 8], Oacc[ht], 0, 0, 0);
        }
    }

    // epilogue: out[b][row][h] = Oacc / l
    #pragma unroll
    for (int r = 0; r < 4; r++) {
        const float inv = 1.0f / l_i[r];
        const int row = q0 + wv * 16 + quad * 4 + r;
        float* orow = &out[((size_t)(b * SEQ + row)) * 128];
        #pragma unroll
        for (int ht = 0; ht < 8; ht++)
            orow[ht * 16 + l16] = Oacc[ht][r] * inv;
    }
}

extern "C" void kernel_launch(void* const* d_in, const int* in_sizes, int n_in,
                              void* d_out, int out_size, void* d_ws, size_t ws_size,
                              hipStream_t stream) {
    const float* emb = (const float*)d_in[0];
    const float* Wk  = (const float*)d_in[1];
    const float* Wq  = (const float*)d_in[2];
    const float* Wv  = (const float*)d_in[3];
    float* out = (float*)d_out;

    const size_t elems = (size_t)BATCH * SEQ * 128;  // 2M bf16 each
    u16* Qws  = (u16*)d_ws;
    u16* Kws  = Qws + elems;
    u16* Vtws = Kws + elems;   // total 12 MB of ws

    qkv_kernel<<<dim3(256), dim3(256), 0, stream>>>(emb, Wk, Wq, Wv, Qws, Kws, Vtws);
    attn_kernel<<<dim3(64, BATCH), dim3(256), 0, stream>>>(Qws, Kws, Vtws, out);
}

// Round 2
// 227.875 us; speedup vs baseline: 1.7798x; 1.7798x over previous
//
#include <hip/hip_runtime.h>
#include <hip/hip_bf16.h>

// SingleHeadAttention: embedded [4,4096,1024] f32; Wk/Wq/Wv [128,1024] f32.
// out = causal_softmax((emb Wq^T)(emb Wk^T)^T / sqrt(128)) (emb Wv^T), f32.
//
// R2 structure:
//  K0 wconv: W f32 -> bf16 [384][1024] in ws (1/sqrt(128) folded into Wq rows).
//  K1 qkv:   GEMM 16384x384x1024, 32 rows/block, grid 512, 8 waves/CU.
//            A via small LDS tile, B direct from L2-resident bf16 W.
//  K2 attn:  flash causal, 128-q-rows/block, Q in regs, split-K (4/2/1 by ws),
//            complement-paired block mapping + batch-per-XCD swizzle.
//  K3 merge: combine split partials (bf16 O, f32 m/l), normalize, write f32 out.
// MFMA layouts (measured m89/m91/m120): A: m=lane&15,k=quad*8+j; B: n=lane&15,
// k=quad*8+j; C/D: col=lane&15,row=quad*4+reg.

#define SEQ 4096
#define BATCH 4
#define HS 128

typedef unsigned short u16;
typedef __bf16 bf16x8 __attribute__((ext_vector_type(8)));
typedef float f32x4 __attribute__((ext_vector_type(4)));

__device__ __forceinline__ u16 f2bf(float f) {
    union { float f; unsigned u; } v; v.f = f;
    unsigned u = v.u;
    return (u16)((u + 0x7FFFu + ((u >> 16) & 1u)) >> 16);  // RNE, finite inputs
}
__device__ __forceinline__ float bf2f(u16 u) {
    union { unsigned u; float f; } v; v.u = ((unsigned)u) << 16; return v.f;
}

// ---------------- K0: W conversion (once) ----------------
// grid 384 x 256. Row r of Wbf[384][1024]: 0-127 K, 128-255 Q (prescaled), 256-383 V.
__global__ __launch_bounds__(256) void wconv_kernel(
    const float* __restrict__ Wk, const float* __restrict__ Wq,
    const float* __restrict__ Wv, u16* __restrict__ Wbf)
{
    const int row = blockIdx.x;
    const float* src = (row < 128) ? Wk : ((row < 256) ? Wq : Wv);
    const float scale = (row >= 128 && row < 256) ? 0.08838834764831845f : 1.0f;
    const int t = threadIdx.x;
    const float4 v = *(const float4*)&src[(size_t)(row & 127) * 1024 + t * 4];
    ushort4 o;
    o.x = f2bf(v.x * scale); o.y = f2bf(v.y * scale);
    o.z = f2bf(v.z * scale); o.w = f2bf(v.w * scale);
    *(ushort4*)&Wbf[(size_t)row * 1024 + t * 4] = o;
}

// ---------------- K1: QKV projection ----------------
// grid 512 x 256 (2 blocks/CU). Block: 32 emb rows x 384 cols; wave w: cols w*96..+95.
__global__ __launch_bounds__(256, 2) void qkv_kernel(
    const float* __restrict__ emb, const u16* __restrict__ Wbf,
    u16* __restrict__ Qws, u16* __restrict__ Kws, u16* __restrict__ Vtws)
{
    __shared__ u16 sE[32][72];   // row stride 144B -> 36 dw -> 4-bank skew, 2-way only

    const int tid  = threadIdx.x;
    const int wv   = tid >> 6;
    const int lane = tid & 63;
    const int quad = lane >> 4;
    const int l16  = lane & 15;
    const int R0   = blockIdx.x * 32;
    const int NC   = wv * 96;

    f32x4 acc[2][6];
    #pragma unroll
    for (int rg = 0; rg < 2; rg++)
        #pragma unroll
        for (int nt = 0; nt < 6; nt++) acc[rg][nt] = (f32x4){0.f, 0.f, 0.f, 0.f};

    for (int kc = 0; kc < 1024; kc += 64) {
        __syncthreads();
        #pragma unroll
        for (int i = 0; i < 2; i++) {            // stage 32x64 f32 -> bf16
            const int idx = tid + i * 256;       // 0..511
            const int row = idx >> 4, c4 = idx & 15;
            const float4 v = *(const float4*)&emb[(size_t)(R0 + row) * 1024 + kc + c4 * 4];
            ushort4 o; o.x = f2bf(v.x); o.y = f2bf(v.y); o.z = f2bf(v.z); o.w = f2bf(v.w);
            *(ushort4*)&sE[row][c4 * 4] = o;
        }
        __syncthreads();

        bf16x8 a[2][2];
        #pragma unroll
        for (int rg = 0; rg < 2; rg++)
            #pragma unroll
            for (int kf = 0; kf < 2; kf++)
                a[rg][kf] = *(const bf16x8*)&sE[rg * 16 + l16][kf * 32 + quad * 8];

        #pragma unroll
        for (int nt = 0; nt < 6; nt++) {
            const u16* wb = &Wbf[(size_t)(NC + nt * 16 + l16) * 1024 + kc];
            const bf16x8 b0 = *(const bf16x8*)&wb[quad * 8];
            const bf16x8 b1 = *(const bf16x8*)&wb[32 + quad * 8];
            #pragma unroll
            for (int rg = 0; rg < 2; rg++) {
                acc[rg][nt] = __builtin_amdgcn_mfma_f32_16x16x32_bf16(a[rg][0], b0, acc[rg][nt], 0, 0, 0);
                acc[rg][nt] = __builtin_amdgcn_mfma_f32_16x16x32_bf16(a[rg][1], b1, acc[rg][nt], 0, 0, 0);
            }
        }
    }

    // epilogue: C/D row = quad*4+reg, col = l16
    #pragma unroll
    for (int nt = 0; nt < 6; nt++) {
        const int col = NC + nt * 16 + l16;   // 0..383, tile never crosses 128-boundary
        const int mat = col >> 7, c = col & 127;
        #pragma unroll
        for (int rg = 0; rg < 2; rg++) {
            const int rowb = R0 + rg * 16 + quad * 4;   // rows rowb..rowb+3, same batch
            if (mat == 2) {
                const int b = rowb >> 12, s0 = rowb & 4095;
                ushort4 o;
                o.x = f2bf(acc[rg][nt][0]); o.y = f2bf(acc[rg][nt][1]);
                o.z = f2bf(acc[rg][nt][2]); o.w = f2bf(acc[rg][nt][3]);
                *(ushort4*)&Vtws[((size_t)(b * HS + c)) * SEQ + s0] = o;   // V^T
            } else {
                u16* dst = (mat == 1) ? Qws : Kws;
                #pragma unroll
                for (int r = 0; r < 4; r++)
                    dst[(size_t)(rowb + r) * HS + c] = f2bf(acc[rg][nt][r]);
            }
        }
    }
}

// ---------------- K2: flash causal attention, split-K ----------------
// 128 q rows/block (wave w: rows w*32..+31, 2 row-groups of 16). 64-key tiles.
// Block L: b = L&3 (XCD-batch affinity), complement pairing over (Q, split).
template<int SPLIT>
__global__ __launch_bounds__(256, 2) void attn_kernel(
    const u16* __restrict__ Qws, const u16* __restrict__ Kws,
    const u16* __restrict__ Vtws, u16* __restrict__ Opart,
    float* __restrict__ ml, float* __restrict__ out)
{
    __shared__ u16 sK[64][136];       // 272B rows -> 4-bank skew, 2-way only
    __shared__ u16 sV[128][72];       // V^T tile [h][key]
    __shared__ u16 sP[4][2][16][72];  // per-wave, per-rowgroup P staging

    const int tid  = threadIdx.x;
    const int wv   = tid >> 6;
    const int lane = tid & 63;
    const int quad = lane >> 4;
    const int l16  = lane & 15;

    const int L = blockIdx.x;
    const int b = L & 3;
    const int u = L >> 2;
    int Q, sp;
    if constexpr (SPLIT == 1) {
        Q = u; sp = 0;
    } else {
        constexpr int half = SPLIT / 2;
        if (u < 32 * half) { Q = u / half; sp = u % half; }
        else { const int v = u - 32 * half; Q = 31 - v / half; sp = half + v % half; }
    }
    const int q0 = Q * 128;
    const int ktmax = 2 * Q + 1;

    // Q fragments in registers (prescaled by 1/sqrt(128) via Wq)
    bf16x8 qf[2][4];
    #pragma unroll
    for (int rg = 0; rg < 2; rg++)
        #pragma unroll
        for (int kf = 0; kf < 4; kf++)
            qf[rg][kf] = *(const bf16x8*)&Qws[((size_t)(b * SEQ + q0 + wv * 32 + rg * 16 + l16)) * HS
                                              + kf * 32 + quad * 8];

    float m_i[2][4], l_i[2][4];
    f32x4 O[2][8];
    #pragma unroll
    for (int rg = 0; rg < 2; rg++)
        #pragma unroll
        for (int r = 0; r < 4; r++) { m_i[rg][r] = -3.0e38f; l_i[rg][r] = 0.f; }
    #pragma unroll
    for (int rg = 0; rg < 2; rg++)
        #pragma unroll
        for (int ht = 0; ht < 8; ht++) O[rg][ht] = (f32x4){0.f, 0.f, 0.f, 0.f};

    for (int kt = sp; kt <= ktmax; kt += SPLIT) {
        const int kb = kt * 64;
        __syncthreads();   // prev-iter readers of sK/sV done
        #pragma unroll
        for (int i = 0; i < 4; i++) {            // K tile [64 x 128]
            const int idx = tid + i * 256;
            const int row = idx >> 4, c8 = idx & 15;
            *(uint4*)&sK[row][c8 * 8] =
                *(const uint4*)&Kws[((size_t)(b * SEQ + kb + row)) * HS + c8 * 8];
        }
        #pragma unroll
        for (int i = 0; i < 4; i++) {            // V^T tile [128 x 64]
            const int idx = tid + i * 256;
            const int h = idx >> 3, k8 = idx & 7;
            *(uint4*)&sV[h][k8 * 8] =
                *(const uint4*)&Vtws[((size_t)(b * HS + h)) * SEQ + kb + k8 * 8];
        }
        __syncthreads();

        // S = Q K^T : per wave [32 q x 64 k], 32 mfma
        f32x4 S[2][4];
        #pragma unroll
        for (int rg = 0; rg < 2; rg++)
            #pragma unroll
            for (int nt = 0; nt < 4; nt++) S[rg][nt] = (f32x4){0.f, 0.f, 0.f, 0.f};
        #pragma unroll
        for (int kf = 0; kf < 4; kf++) {
            bf16x8 kfr[4];
            #pragma unroll
            for (int nt = 0; nt < 4; nt++)
                kfr[nt] = *(const bf16x8*)&sK[nt * 16 + l16][kf * 32 + quad * 8];
            #pragma unroll
            for (int rg = 0; rg < 2; rg++)
                #pragma unroll
                for (int nt = 0; nt < 4; nt++)
                    S[rg][nt] = __builtin_amdgcn_mfma_f32_16x16x32_bf16(qf[rg][kf], kfr[nt], S[rg][nt], 0, 0, 0);
        }

        const bool diag = (kt >= 2 * Q);   // only diagonal-straddling tiles mask
        #pragma unroll
        for (int rg = 0; rg < 2; rg++) {
            const int qg = q0 + wv * 32 + rg * 16 + quad * 4;
            #pragma unroll
            for (int r = 0; r < 4; r++) {
                if (diag) {
                    #pragma unroll
                    for (int nt = 0; nt < 4; nt++)
                        if (kb + nt * 16 + l16 > qg + r) S[rg][nt][r] = -3.0e38f;
                }
                float mx = fmaxf(fmaxf(S[0 + rg][0][r], S[rg][1][r]), fmaxf(S[rg][2][r], S[rg][3][r]));
                mx = fmaxf(mx, __shfl_xor(mx, 1));
                mx = fmaxf(mx, __shfl_xor(mx, 2));
                mx = fmaxf(mx, __shfl_xor(mx, 4));
                mx = fmaxf(mx, __shfl_xor(mx, 8));
                // clamp: fully-masked row -> p underflows to 0, l stays 0
                const float mnew = fmaxf(fmaxf(m_i[rg][r], mx), -1.0e30f);
                const float alpha = exp2f((m_i[rg][r] - mnew) * 1.4426950408889634f);
                m_i[rg][r] = mnew;
                float rs = 0.f;
                #pragma unroll
                for (int nt = 0; nt < 4; nt++) {
                    const float p = exp2f((S[rg][nt][r] - mnew) * 1.4426950408889634f);
                    S[rg][nt][r] = p;
                    rs += p;
                }
                rs += __shfl_xor(rs, 1);
                rs += __shfl_xor(rs, 2);
                rs += __shfl_xor(rs, 4);
                rs += __shfl_xor(rs, 8);
                l_i[rg][r] = l_i[rg][r] * alpha + rs;
                #pragma unroll
                for (int ht = 0; ht < 8; ht++) O[rg][ht][r] *= alpha;
            }
        }

        // P: C-layout -> LDS (per-wave region; same-wave RAW ordered by lgkmcnt)
        #pragma unroll
        for (int rg = 0; rg < 2; rg++)
            #pragma unroll
            for (int r = 0; r < 4; r++)
                #pragma unroll
                for (int nt = 0; nt < 4; nt++)
                    sP[wv][rg][quad * 4 + r][nt * 16 + l16] = f2bf(S[rg][nt][r]);

        bf16x8 pf[2][2];
        #pragma unroll
        for (int rg = 0; rg < 2; rg++)
            #pragma unroll
            for (int kf2 = 0; kf2 < 2; kf2++)
                pf[rg][kf2] = *(const bf16x8*)&sP[wv][rg][l16][kf2 * 32 + quad * 8];

        // O += P V : 32 mfma
        #pragma unroll
        for (int ht = 0; ht < 8; ht++) {
            const u16* vr = sV[ht * 16 + l16];
            const bf16x8 v0 = *(const bf16x8*)&vr[quad * 8];
            const bf16x8 v1 = *(const bf16x8*)&vr[32 + quad * 8];
            #pragma unroll
            for (int rg = 0; rg < 2; rg++) {
                O[rg][ht] = __builtin_amdgcn_mfma_f32_16x16x32_bf16(pf[rg][0], v0, O[rg][ht], 0, 0, 0);
                O[rg][ht] = __builtin_amdgcn_mfma_f32_16x16x32_bf16(pf[rg][1], v1, O[rg][ht], 0, 0, 0);
            }
        }
    }

    if constexpr (SPLIT == 1) {
        // direct: normalize and write f32 out
        #pragma unroll
        for (int rg = 0; rg < 2; rg++)
            #pragma unroll
            for (int r = 0; r < 4; r++) {
                const float inv = 1.0f / l_i[rg][r];
                const int row = q0 + wv * 32 + rg * 16 + quad * 4 + r;
                float* orow = &out[((size_t)(b * SEQ + row)) * HS];
                #pragma unroll
                for (int ht = 0; ht < 8; ht++)
                    orow[ht * 16 + l16] = O[rg][ht][r] * inv;
            }
    } else {
        // write un-normalized bf16 partial + (m,l)
        const size_t pbase = ((size_t)(sp * BATCH + b)) * SEQ * HS;
        #pragma unroll
        for (int rg = 0; rg < 2; rg++)
            #pragma unroll
            for (int r = 0; r < 4; r++) {
                const int row = q0 + wv * 32 + rg * 16 + quad * 4 + r;
                #pragma unroll
                for (int ht = 0; ht < 8; ht++)
                    Opart[pbase + (size_t)row * HS + ht * 16 + l16] = f2bf(O[rg][ht][r]);
            }
        if (l16 == 0) {
            #pragma unroll
            for (int rg = 0; rg < 2; rg++)
                #pragma unroll
                for (int r = 0; r < 4; r++) {
                    const int row = q0 + wv * 32 + rg * 16 + quad * 4 + r;
                    float2 v; v.x = m_i[rg][r]; v.y = l_i[rg][r];
                    *(float2*)&ml[((size_t)(sp * BATCH + b) * SEQ + row) * 2] = v;
                }
        }
    }
}

// ---------------- K3: merge split partials ----------------
// grid BATCH*SEQ/8 x 256: 8 rows/block, 32 thr/row, 4 f32 out per thread.
template<int SPLIT>
__global__ __launch_bounds__(256) void merge_kernel(
    const u16* __restrict__ Opart, const float* __restrict__ ml,
    float* __restrict__ out)
{
    const int t = threadIdx.x;
    const int gr = blockIdx.x * 8 + (t >> 5);    // 0..16383
    const int c4 = (t & 31) * 4;
    const int b = gr >> 12, si = gr & 4095;

    float m[SPLIT], l[SPLIT];
    float M = -3.4e38f;
    #pragma unroll
    for (int s = 0; s < SPLIT; s++) {
        const float2 v = *(const float2*)&ml[((size_t)(s * BATCH + b) * SEQ + si) * 2];
        m[s] = v.x; l[s] = v.y;
        M = fmaxf(M, m[s]);
    }
    float den = 0.f;
    f32x4 num = (f32x4){0.f, 0.f, 0.f, 0.f};
    #pragma unroll
    for (int s = 0; s < SPLIT; s++) {
        const float w = exp2f((m[s] - M) * 1.4426950408889634f);
        den += w * l[s];
        const ushort4 o = *(const ushort4*)&Opart[((size_t)(s * BATCH + b) * SEQ + si) * HS + c4];
        num[0] += w * bf2f(o.x); num[1] += w * bf2f(o.y);
        num[2] += w * bf2f(o.z); num[3] += w * bf2f(o.w);
    }
    const float inv = 1.0f / den;
    float4 o; o.x = num[0] * inv; o.y = num[1] * inv; o.z = num[2] * inv; o.w = num[3] * inv;
    *(float4*)&out[(size_t)gr * HS + c4] = o;
}

extern "C" void kernel_launch(void* const* d_in, const int* in_sizes, int n_in,
                              void* d_out, int out_size, void* d_ws, size_t ws_size,
                              hipStream_t stream) {
    const float* emb = (const float*)d_in[0];
    const float* Wk  = (const float*)d_in[1];
    const float* Wq  = (const float*)d_in[2];
    const float* Wv  = (const float*)d_in[3];
    float* out = (float*)d_out;

    char* ws = (char*)d_ws;
    const size_t WBF_OFF   = 0;
    const size_t WBF_SZ    = (size_t)384 * 1024 * 2;                 // 768 KB
    const size_t Q_OFF     = WBF_OFF + WBF_SZ;
    const size_t QKV_SZ    = (size_t)BATCH * SEQ * HS * 2;           // 4 MB each
    const size_t K_OFF     = Q_OFF + QKV_SZ;
    const size_t VT_OFF    = K_OFF + QKV_SZ;
    const size_t OPART_OFF = VT_OFF + QKV_SZ;
    const size_t OPART_1   = (size_t)BATCH * SEQ * HS * 2;           // per split, 4 MB
    const size_t ML_1      = (size_t)BATCH * SEQ * 2 * 4;            // per split, 128 KB

    u16* Wbf  = (u16*)(ws + WBF_OFF);
    u16* Qws  = (u16*)(ws + Q_OFF);
    u16* Kws  = (u16*)(ws + K_OFF);
    u16* Vtws = (u16*)(ws + VT_OFF);

    const size_t need4 = OPART_OFF + 4 * (OPART_1 + ML_1);
    const size_t need2 = OPART_OFF + 2 * (OPART_1 + ML_1);

    wconv_kernel<<<dim3(384), dim3(256), 0, stream>>>(Wk, Wq, Wv, Wbf);
    qkv_kernel<<<dim3(512), dim3(256), 0, stream>>>(emb, Wbf, Qws, Kws, Vtws);

    if (ws_size >= need4) {
        u16*   Opart = (u16*)(ws + OPART_OFF);
        float* ml    = (float*)(ws + OPART_OFF + 4 * OPART_1);
        attn_kernel<4><<<dim3(32 * BATCH * 4), dim3(256), 0, stream>>>(Qws, Kws, Vtws, Opart, ml, out);
        merge_kernel<4><<<dim3(BATCH * SEQ / 8), dim3(256), 0, stream>>>(Opart, ml, out);
    } else if (ws_size >= need2) {
        u16*   Opart = (u16*)(ws + OPART_OFF);
        float* ml    = (float*)(ws + OPART_OFF + 2 * OPART_1);
        attn_kernel<2><<<dim3(32 * BATCH * 2), dim3(256), 0, stream>>>(Qws, Kws, Vtws, Opart, ml, out);
        merge_kernel<2><<<dim3(BATCH * SEQ / 8), dim3(256), 0, stream>>>(Opart, ml, out);
    } else {
        attn_kernel<1><<<dim3(32 * BATCH), dim3(256), 0, stream>>>(Qws, Kws, Vtws, nullptr, nullptr, out);
    }
}